// Round 9
// baseline (225.662 us; speedup 1.0000x reference)
//
#include <hip/hip_runtime.h>
#include <hip/hip_bf16.h>

// Problem constants (fixed by reference)
constexpr int NN   = 50000;   // nodes
constexpr int NE   = 800000;  // edges per relation
constexpr int NR   = 3;       // relations
constexpr int DIN  = 96;
constexpr int DH   = 96;
constexpr int DOUT = 64;
constexpr int SLOT = 64;      // max in-degree slots (Poisson(16): P(>64) ~ 1e-22)
constexpr int ZROW = NN;      // reserved all-zero feature row (padding target)

// Binning parameters (zero global atomics; block-private runs + scan offsets)
constexpr int NBUCK   = 196;       // bucket = dst >> 8 (256 nodes per bucket)
constexpr int LCAP    = 56;        // per-(block,bucket) cap
constexpr int P1B     = 256;       // scatter blocks per relation
constexpr int CHUNK   = NE / P1B;  // 3125 edges per block (exact)
constexpr int BSTRIDE = 3200;      // gbuck ints per block
constexpr int LSTRIDE = 200;       // lofs ints per block (197 used)
constexpr int NWIN    = NR * NBUCK; // 588 sort windows (256 nodes each)

// Fused prep kernel block ranges
constexpr int SCAT_BLKS = NR * P1B;                 // 768
constexpr int CONV_BLKS = (NN * 96 + 4095) / 4096;  // 1172
constexpr int WT_ELEMS  = 2 * NR * DIN * DH + 2 * NR * DH * DOUT;  // 92160
constexpr int WT_BLKS   = (WT_ELEMS + 511) / 512;   // 180
constexpr int PREP_GRID = SCAT_BLKS + CONV_BLKS + WT_BLKS;

typedef __attribute__((ext_vector_type(8))) short bf16x8;  // MFMA A/B frag
typedef __attribute__((ext_vector_type(4))) float f32x4;   // MFMA C/D frag

// ---- bf16 helpers (RNE) ----------------------------------------------------
__device__ __forceinline__ unsigned short f2b(float f) {
    unsigned int u = __float_as_uint(f);
    u += 0x7fffu + ((u >> 16) & 1u);
    return (unsigned short)(u >> 16);
}
__device__ __forceinline__ float blo(unsigned int u) { return __uint_as_float(u << 16); }
__device__ __forceinline__ float bhi(unsigned int u) { return __uint_as_float(u & 0xffff0000u); }
__device__ __forceinline__ unsigned int pack2(float lo, float hi) {
    return (unsigned int)f2b(lo) | ((unsigned int)f2b(hi) << 16);
}

struct __align__(4) U3 { unsigned int x, y, z; };

// ---------------------------------------------------------------------------
// Fused prep: [0,768) edge scatter; [768,1940) x f32->bf16 (+zero row);
// [1940,2120) weight transposes f32->bf16.
// ---------------------------------------------------------------------------
__global__ __launch_bounds__(512)
void prep_kernel(const int* __restrict__ src,
                 const int* __restrict__ dst,
                 unsigned int* __restrict__ gbuck,
                 int* __restrict__ glofs,
                 const float* __restrict__ x,
                 unsigned short* __restrict__ xb,    // [(NN+1)][96]
                 const float* __restrict__ Ws1, const float* __restrict__ Wn1,
                 const float* __restrict__ Ws2, const float* __restrict__ Wn2,
                 unsigned short* __restrict__ wt)
{
    __shared__ unsigned int lbuf[NBUCK][LCAP];
    __shared__ int lcnt[NBUCK];
    __shared__ int sa[256], sb[256];
    __shared__ int lofs[NBUCK + 1];

    const int bid = blockIdx.x;
    const int tid = threadIdx.x;

    if (bid < SCAT_BLKS) {
        const int r = bid >> 8, c = bid & 255;
        for (int i = tid; i < NBUCK; i += 512) lcnt[i] = 0;
        __syncthreads();

        const int* sr = src + (size_t)r * NE + (size_t)c * CHUNK;
        const int* dr = dst + (size_t)r * NE + (size_t)c * CHUNK;
        for (int i = tid; i < CHUNK; i += 512) {
            int d = dr[i];
            int s = sr[i];
            int b = d >> 8;
            int pos = atomicAdd(&lcnt[b], 1);
            if (pos < LCAP)
                lbuf[b][pos] = ((unsigned int)(d & 255) << 16) | (unsigned int)s;
        }
        __syncthreads();

        if (tid < 256)
            sa[tid] = (tid < NBUCK) ? min(lcnt[tid], LCAP) : 0;
        __syncthreads();
        int* cur = sa; int* nxt = sb;
        for (int st = 1; st < 256; st <<= 1) {
            if (tid < 256) {
                int v = cur[tid];
                if (tid >= st) v += cur[tid - st];
                nxt[tid] = v;
            }
            __syncthreads();
            int* t2 = cur; cur = nxt; nxt = t2;
        }
        if (tid == 0) lofs[0] = 0;
        if (tid < NBUCK) lofs[tid + 1] = cur[tid];
        __syncthreads();

        if (tid < NBUCK + 1) glofs[(size_t)bid * LSTRIDE + tid] = lofs[tid];

        const int w = tid >> 6, l = tid & 63;
        unsigned int* gb = gbuck + (size_t)bid * BSTRIDE;
        for (int b = w; b < NBUCK; b += 8) {
            int cnt = min(lcnt[b], LCAP);
            if (l < cnt) gb[lofs[b] + l] = lbuf[b][l];
        }
    } else if (bid < SCAT_BLKS + CONV_BLKS) {
        const int rb = bid - SCAT_BLKS;
        if (rb == 0 && tid < 48) {
            unsigned int* z = reinterpret_cast<unsigned int*>(xb + (size_t)ZROW * 96);
            z[tid] = 0u;
        }
        int i = (rb * 512 + tid) * 8;
        if (i < NN * 96) {
            float4 a = *reinterpret_cast<const float4*>(x + i);
            float4 b = *reinterpret_cast<const float4*>(x + i + 4);
            uint4 o;
            o.x = pack2(a.x, a.y);
            o.y = pack2(a.z, a.w);
            o.z = pack2(b.x, b.y);
            o.w = pack2(b.z, b.w);
            *reinterpret_cast<uint4*>(xb + i) = o;
        }
    } else {
        int g = (bid - SCAT_BLKS - CONV_BLKS) * 512 + tid;
        if (g < WT_ELEMS) {
            constexpr int SZ1 = NR * DIN * DH;
            constexpr int SZ2 = NR * DH * DOUT;
            const float* in;
            int idx, KD, ND;
            if (g < SZ1)                { in = Ws1; idx = g;                 KD = DIN; ND = DH; }
            else if (g < 2 * SZ1)       { in = Wn1; idx = g - SZ1;           KD = DIN; ND = DH; }
            else if (g < 2 * SZ1 + SZ2) { in = Ws2; idx = g - 2 * SZ1;       KD = DH;  ND = DOUT; }
            else                        { in = Wn2; idx = g - 2 * SZ1 - SZ2; KD = DH;  ND = DOUT; }
            int k = idx % KD;
            int rn = idx / KD;
            int n = rn % ND;
            int r = rn / ND;
            wt[g] = f2b(in[((size_t)r * KD + k) * ND + n]);
        }
    }
}

// ---------------------------------------------------------------------------
// Binning phase B + per-window degree sort. One block per (relation,bucket):
// LDS-bin into 256-node slot lists (ZROW-padded), write slots + deg coalesced,
// and emit a degree-descending permutation `order` of the window's nodes so
// agg waves process similar-degree nodes together.
// ---------------------------------------------------------------------------
__global__ __launch_bounds__(512)
void bin_build_kernel(const unsigned int* __restrict__ gbuck,
                      const int* __restrict__ glofs,
                      unsigned short* __restrict__ slots,   // [NR*NN][SLOT]
                      int* __restrict__ deg,                // [NR*NN]
                      unsigned short* __restrict__ order)   // [NWIN*256]
{
    __shared__ unsigned short lslot[256][SLOT];   // 32 KB
    __shared__ int lcnt[256];
    __shared__ unsigned short sord[256];

    const int rb = blockIdx.x;                    // 0 .. NWIN-1
    const int r  = rb / NBUCK, b = rb - r * NBUCK;
    const int nbase = b * 256;
    int nb = NN - nbase; if (nb > 256) nb = 256;
    const int tid = threadIdx.x;

    unsigned int* ls32i = reinterpret_cast<unsigned int*>(&lslot[0][0]);
    for (int i = tid; i < 256 * SLOT / 2; i += 512) ls32i[i] = 0xC350C350u; // ZROW pad
    for (int i = tid; i < 256; i += 512) lcnt[i] = 0;
    if (tid < 128) reinterpret_cast<unsigned int*>(sord)[tid] = 0xFFFFFFFFu;
    __syncthreads();

    const int blk  = tid >> 1;
    const int half = tid & 1;
    const int gblk = r * P1B + blk;
    int o0 = glofs[(size_t)gblk * LSTRIDE + b];
    int o1 = glofs[(size_t)gblk * LSTRIDE + b + 1];
    const unsigned int* run = gbuck + (size_t)gblk * BSTRIDE + o0;
    int cnt = o1 - o0;
    for (int i = half; i < cnt; i += 2) {
        unsigned int e = run[i];
        int nl = e >> 16;
        int pos = atomicAdd(&lcnt[nl], 1);
        if (pos < SLOT) lslot[nl][pos] = (unsigned short)(e & 0xffffu);
    }
    __syncthreads();

    // true degree out
    for (int j = tid; j < nb; j += 512) deg[r * NN + nbase + j] = lcnt[j];

    // degree-descending rank (O(256) per thread, LDS broadcast reads)
    if (tid < 256) {
        const int j = tid;
        const int myk = (j < nb) ? lcnt[j] : -1;
        int rank = 0;
        #pragma unroll 8
        for (int k = 0; k < 256; ++k) {
            int kk = (k < nb) ? lcnt[k] : -1;
            rank += (kk > myk) || (kk == myk && k < j);
        }
        if (j < nb) sord[rank] = (unsigned short)j;
    }
    __syncthreads();

    if (tid < 128)
        reinterpret_cast<unsigned int*>(order + (size_t)rb * 256)[tid] =
            reinterpret_cast<const unsigned int*>(sord)[tid];

    const unsigned int* ls32 = reinterpret_cast<const unsigned int*>(&lslot[0][0]);
    unsigned int* gs32 = reinterpret_cast<unsigned int*>(
        slots + ((size_t)r * NN + nbase) * SLOT);
    const int tot = nb * (SLOT / 2);
    for (int i = tid; i < tot; i += 512) gs32[i] = ls32[i];
}

// ---- shared decode for degree-sorted agg groups ----------------------------
__device__ __forceinline__ bool agg_decode(const unsigned short* __restrict__ order,
                                           int g, int& r, int& node, int& grp)
{
    int rb = g >> 8;
    int ordv = order[g];
    if (ordv == 0xFFFF) return false;            // window pad (last bucket < 256)
    r = rb / NBUCK;
    int b = rb - r * NBUCK;
    node = (b << 8) + ordv;
    grp = r * NN + node;
    return true;
}

// ---------------------------------------------------------------------------
// Mean-aggregation, 96-dim rows (layer 1 / fallback). 16 lanes per group;
// lane t gathers 12B of each 192B row; branch-free 8-edge batches, ZROW pad.
// ---------------------------------------------------------------------------
__global__ __launch_bounds__(256)
void agg96_kernel(const unsigned int* __restrict__ Hb,        // [(NN+1)][48]
                  const unsigned short* __restrict__ slots,
                  const int* __restrict__ deg,
                  const unsigned short* __restrict__ order,
                  unsigned int* __restrict__ aggb)            // [NR][NN][48]
{
    int gid = blockIdx.x * 256 + threadIdx.x;
    int g = gid >> 4, t = gid & 15;
    int r, node, grp;
    if (!agg_decode(order, g, r, node, grp)) return;
    const uint4* sl4 = reinterpret_cast<const uint4*>(slots + (size_t)grp * SLOT);
    int e = deg[grp];
    if (e > SLOT) e = SLOT;

    uint4 iv0 = sl4[0], iv1 = sl4[1], iv2 = sl4[2], iv3 = sl4[3];
    float a0 = 0.f, a1 = 0.f, a2 = 0.f, a3 = 0.f, a4 = 0.f, a5 = 0.f;

#define DO8(V)                                                                 \
    {                                                                          \
        unsigned int i0 = (V).x & 0xffffu, i1 = (V).x >> 16;                   \
        unsigned int i2 = (V).y & 0xffffu, i3 = (V).y >> 16;                   \
        unsigned int i4 = (V).z & 0xffffu, i5 = (V).z >> 16;                   \
        unsigned int i6 = (V).w & 0xffffu, i7 = (V).w >> 16;                   \
        U3 g0 = *reinterpret_cast<const U3*>(Hb + (size_t)i0 * 48 + 3 * t);    \
        U3 g1 = *reinterpret_cast<const U3*>(Hb + (size_t)i1 * 48 + 3 * t);    \
        U3 g2 = *reinterpret_cast<const U3*>(Hb + (size_t)i2 * 48 + 3 * t);    \
        U3 g3 = *reinterpret_cast<const U3*>(Hb + (size_t)i3 * 48 + 3 * t);    \
        U3 g4 = *reinterpret_cast<const U3*>(Hb + (size_t)i4 * 48 + 3 * t);    \
        U3 g5 = *reinterpret_cast<const U3*>(Hb + (size_t)i5 * 48 + 3 * t);    \
        U3 g6 = *reinterpret_cast<const U3*>(Hb + (size_t)i6 * 48 + 3 * t);    \
        U3 g7 = *reinterpret_cast<const U3*>(Hb + (size_t)i7 * 48 + 3 * t);    \
        a0 += blo(g0.x) + blo(g1.x) + blo(g2.x) + blo(g3.x)                    \
            + blo(g4.x) + blo(g5.x) + blo(g6.x) + blo(g7.x);                   \
        a1 += bhi(g0.x) + bhi(g1.x) + bhi(g2.x) + bhi(g3.x)                    \
            + bhi(g4.x) + bhi(g5.x) + bhi(g6.x) + bhi(g7.x);                   \
        a2 += blo(g0.y) + blo(g1.y) + blo(g2.y) + blo(g3.y)                    \
            + blo(g4.y) + blo(g5.y) + blo(g6.y) + blo(g7.y);                   \
        a3 += bhi(g0.y) + bhi(g1.y) + bhi(g2.y) + bhi(g3.y)                    \
            + bhi(g4.y) + bhi(g5.y) + bhi(g6.y) + bhi(g7.y);                   \
        a4 += blo(g0.z) + blo(g1.z) + blo(g2.z) + blo(g3.z)                    \
            + blo(g4.z) + blo(g5.z) + blo(g6.z) + blo(g7.z);                   \
        a5 += bhi(g0.z) + bhi(g1.z) + bhi(g2.z) + bhi(g3.z)                    \
            + bhi(g4.z) + bhi(g5.z) + bhi(g6.z) + bhi(g7.z);                   \
    }

    int nb8 = (e + 7) >> 3;
    if (nb8 > 0) DO8(iv0);
    if (nb8 > 1) DO8(iv1);
    if (nb8 > 2) DO8(iv2);
    if (nb8 > 3) DO8(iv3);
    for (int i = 32; i < e; i += 8) {
        uint4 v = sl4[i >> 3];
        DO8(v);
    }
#undef DO8

    float inv = 1.0f / (float)(e > 0 ? e : 1);
    unsigned int* o = aggb + (size_t)grp * 48 + 3 * t;
    o[0] = pack2(a0 * inv, a1 * inv);
    o[1] = pack2(a2 * inv, a3 * inv);
    o[2] = pack2(a4 * inv, a5 * inv);
}

// ---------------------------------------------------------------------------
// Mean-aggregation of Wn-TRANSFORMED 64-dim rows (layer 2 fast path).
// Gathers y2_r[(NN+1)][64] per relation; lane t reads 8B (dwordx2) per row.
// ---------------------------------------------------------------------------
__global__ __launch_bounds__(256)
void agg64_kernel(const unsigned int* __restrict__ y2,        // [NR][(NN+1)][32]
                  const unsigned short* __restrict__ slots,
                  const int* __restrict__ deg,
                  const unsigned short* __restrict__ order,
                  unsigned int* __restrict__ aggY2)           // [NR][NN][32]
{
    int gid = blockIdx.x * 256 + threadIdx.x;
    int g = gid >> 4, t = gid & 15;
    int r, node, grp;
    if (!agg_decode(order, g, r, node, grp)) return;
    const unsigned int* Tp = y2 + (size_t)r * ((size_t)(NN + 1) * 32);
    const uint4* sl4 = reinterpret_cast<const uint4*>(slots + (size_t)grp * SLOT);
    int e = deg[grp];
    if (e > SLOT) e = SLOT;

    uint4 iv0 = sl4[0], iv1 = sl4[1], iv2 = sl4[2], iv3 = sl4[3];
    float a0 = 0.f, a1 = 0.f, a2 = 0.f, a3 = 0.f;

#define DO8W(V)                                                                \
    {                                                                          \
        unsigned int i0 = (V).x & 0xffffu, i1 = (V).x >> 16;                   \
        unsigned int i2 = (V).y & 0xffffu, i3 = (V).y >> 16;                   \
        unsigned int i4 = (V).z & 0xffffu, i5 = (V).z >> 16;                   \
        unsigned int i6 = (V).w & 0xffffu, i7 = (V).w >> 16;                   \
        uint2 g0 = *reinterpret_cast<const uint2*>(Tp + (size_t)i0 * 32 + 2 * t); \
        uint2 g1 = *reinterpret_cast<const uint2*>(Tp + (size_t)i1 * 32 + 2 * t); \
        uint2 g2 = *reinterpret_cast<const uint2*>(Tp + (size_t)i2 * 32 + 2 * t); \
        uint2 g3 = *reinterpret_cast<const uint2*>(Tp + (size_t)i3 * 32 + 2 * t); \
        uint2 g4 = *reinterpret_cast<const uint2*>(Tp + (size_t)i4 * 32 + 2 * t); \
        uint2 g5 = *reinterpret_cast<const uint2*>(Tp + (size_t)i5 * 32 + 2 * t); \
        uint2 g6 = *reinterpret_cast<const uint2*>(Tp + (size_t)i6 * 32 + 2 * t); \
        uint2 g7 = *reinterpret_cast<const uint2*>(Tp + (size_t)i7 * 32 + 2 * t); \
        a0 += blo(g0.x) + blo(g1.x) + blo(g2.x) + blo(g3.x)                    \
            + blo(g4.x) + blo(g5.x) + blo(g6.x) + blo(g7.x);                   \
        a1 += bhi(g0.x) + bhi(g1.x) + bhi(g2.x) + bhi(g3.x)                    \
            + bhi(g4.x) + bhi(g5.x) + bhi(g6.x) + bhi(g7.x);                   \
        a2 += blo(g0.y) + blo(g1.y) + blo(g2.y) + blo(g3.y)                    \
            + blo(g4.y) + blo(g5.y) + blo(g6.y) + blo(g7.y);                   \
        a3 += bhi(g0.y) + bhi(g1.y) + bhi(g2.y) + bhi(g3.y)                    \
            + bhi(g4.y) + bhi(g5.y) + bhi(g6.y) + bhi(g7.y);                   \
    }

    int nb8 = (e + 7) >> 3;
    if (nb8 > 0) DO8W(iv0);
    if (nb8 > 1) DO8W(iv1);
    if (nb8 > 2) DO8W(iv2);
    if (nb8 > 3) DO8W(iv3);
    for (int i = 32; i < e; i += 8) {
        uint4 v = sl4[i >> 3];
        DO8W(v);
    }
#undef DO8W

    float inv = 1.0f / (float)(e > 0 ? e : 1);
    unsigned int* o = aggY2 + (size_t)grp * 32 + 2 * t;
    o[0] = pack2(a0 * inv, a1 * inv);
    o[1] = pack2(a2 * inv, a3 * inv);
}

// ---------------------------------------------------------------------------
// y2_r = h1 @ Wn2_r for all 3 relations (dense MFMA), bf16 out, ZROW zeroed.
// ---------------------------------------------------------------------------
__global__ __launch_bounds__(256)
void y2_kernel(const unsigned short* __restrict__ Hb,   // h1 [(NN+1)][96]
               const unsigned short* __restrict__ Wtn,  // [NR][64][96] (Wn2^T)
               unsigned short* __restrict__ y2)         // [NR][(NN+1)][64]
{
    if (blockIdx.x == 0 && threadIdx.x < 96) {
        unsigned int* z = reinterpret_cast<unsigned int*>(y2);
        int r = threadIdx.x >> 5, d = threadIdx.x & 31;
        z[((size_t)r * (NN + 1) + ZROW) * 32 + d] = 0u;
    }
    const int w    = threadIdx.x >> 6;
    const int l    = threadIdx.x & 63;
    const int n0   = blockIdx.x * 64 + w * 16;
    const int arow = l & 15, asel = l >> 4;
    int na = n0 + arow;
    if (na > NN - 1) na = NN - 1;

    bf16x8 ax[3];
    const unsigned short* xr = Hb + (size_t)na * 96 + asel * 8;
    #pragma unroll
    for (int kb = 0; kb < 3; ++kb)
        ax[kb] = *reinterpret_cast<const bf16x8*>(xr + kb * 32);

    #pragma unroll
    for (int c = 0; c < 4; ++c) {
        f32x4 acc[NR];
        #pragma unroll
        for (int r = 0; r < NR; ++r) acc[r] = (f32x4){0.f, 0.f, 0.f, 0.f};
        #pragma unroll
        for (int r = 0; r < NR; ++r) {
            const unsigned short* bn = Wtn + ((size_t)r * DOUT + c * 16 + arow) * 96 + asel * 8;
            #pragma unroll
            for (int kb = 0; kb < 3; ++kb)
                acc[r] = __builtin_amdgcn_mfma_f32_16x16x32_bf16(
                    ax[kb], *reinterpret_cast<const bf16x8*>(bn + kb * 32), acc[r], 0, 0, 0);
        }
        const int col = c * 16 + arow;
        #pragma unroll
        for (int r = 0; r < NR; ++r)
            #pragma unroll
            for (int j = 0; j < 4; ++j) {
                int node = n0 + asel * 4 + j;
                if (node < NN)
                    y2[((size_t)r * (NN + 1) + node) * 64 + col] = f2b(acc[r][j]);
            }
    }
}

// ---------------------------------------------------------------------------
// MFMA layer. PRE_AGG=false: acc = X@Ws_r + AGG_r@Wn_r (aggb raw means).
// PRE_AGG=true:  acc initialized from pre-transformed aggY2_r, Ws MFMAs only.
// ---------------------------------------------------------------------------
template <int NOUT, bool OUT16, bool PRE_AGG>
__global__ __launch_bounds__(256)
void mfma_layer_kernel(const unsigned short* Hb,                // [(NN+1)][96] (may alias o16)
                       const unsigned short* __restrict__ aggb, // [NR][NN][96] (if !PRE_AGG)
                       const unsigned short* __restrict__ aggY2,// [NR][NN][NOUT] (if PRE_AGG)
                       const unsigned short* __restrict__ Wts,  // [NR][NOUT][96]
                       const unsigned short* __restrict__ Wtn,  // [NR][NOUT][96]
                       const float* __restrict__ bias,          // [NR][NOUT]
                       unsigned short* o16,                     // [(NN+1)][96]
                       float* __restrict__ o32)                 // [NN][NOUT]
{
    const int w    = threadIdx.x >> 6;
    const int l    = threadIdx.x & 63;
    const int n0   = blockIdx.x * 64 + w * 16;
    const int arow = l & 15, asel = l >> 4;
    int na = n0 + arow;
    if (na > NN - 1) na = NN - 1;

    bf16x8 ax[3], ag[NR][3];
    {
        const unsigned short* xr = Hb + (size_t)na * 96 + asel * 8;
        #pragma unroll
        for (int kb = 0; kb < 3; ++kb)
            ax[kb] = *reinterpret_cast<const bf16x8*>(xr + kb * 32);
        if (!PRE_AGG) {
            #pragma unroll
            for (int r = 0; r < NR; ++r) {
                const unsigned short* gr = aggb + ((size_t)r * NN + na) * 96 + asel * 8;
                #pragma unroll
                for (int kb = 0; kb < 3; ++kb)
                    ag[r][kb] = *reinterpret_cast<const bf16x8*>(gr + kb * 32);
            }
        }
    }

    constexpr int NC = NOUT / 16;
    #pragma unroll
    for (int c = 0; c < NC; ++c) {
        const int col = c * 16 + arow;
        f32x4 acc[NR];
        if (PRE_AGG) {
            #pragma unroll
            for (int r = 0; r < NR; ++r)
                #pragma unroll
                for (int j = 0; j < 4; ++j) {
                    int nj = n0 + asel * 4 + j;
                    if (nj > NN - 1) nj = NN - 1;
                    unsigned short hv = aggY2[((size_t)r * NN + nj) * NOUT + col];
                    acc[r][j] = __uint_as_float((unsigned int)hv << 16);
                }
        } else {
            #pragma unroll
            for (int r = 0; r < NR; ++r) acc[r] = (f32x4){0.f, 0.f, 0.f, 0.f};
        }

        #pragma unroll
        for (int r = 0; r < NR; ++r) {
            const unsigned short* bs = Wts + ((size_t)r * NOUT + c * 16 + arow) * 96 + asel * 8;
            #pragma unroll
            for (int kb = 0; kb < 3; ++kb) {
                acc[r] = __builtin_amdgcn_mfma_f32_16x16x32_bf16(
                    ax[kb], *reinterpret_cast<const bf16x8*>(bs + kb * 32), acc[r], 0, 0, 0);
                if (!PRE_AGG) {
                    const unsigned short* bn = Wtn + ((size_t)r * NOUT + c * 16 + arow) * 96 + asel * 8;
                    acc[r] = __builtin_amdgcn_mfma_f32_16x16x32_bf16(
                        ag[r][kb], *reinterpret_cast<const bf16x8*>(bn + kb * 32), acc[r], 0, 0, 0);
                }
            }
        }

        const float b0 = bias[col];
        const float b1 = bias[NOUT + col];
        const float b2 = bias[2 * NOUT + col];
        #pragma unroll
        for (int j = 0; j < 4; ++j) {
            int node = n0 + asel * 4 + j;
            if (node < NN) {
                float v = (tanhf(acc[0][j] + b0) + tanhf(acc[1][j] + b1)
                         + tanhf(acc[2][j] + b2)) * (1.0f / 3.0f);
                if (OUT16) o16[(size_t)node * 96 + col] = f2b(v);
                else       o32[(size_t)node * DOUT + col] = v;
            }
        }
    }
}

// ---------------------------------------------------------------------------
extern "C" void kernel_launch(void* const* d_in, const int* in_sizes, int n_in,
                              void* d_out, int out_size, void* d_ws, size_t ws_size,
                              hipStream_t stream)
{
    const float* x   = (const float*)d_in[0];
    const int*   src = (const int*)d_in[1];
    const int*   dst = (const int*)d_in[2];
    const float* Ws1 = (const float*)d_in[3];
    const float* Wn1 = (const float*)d_in[4];
    const float* b1  = (const float*)d_in[5];
    const float* Ws2 = (const float*)d_in[6];
    const float* Wn2 = (const float*)d_in[7];
    const float* b2  = (const float*)d_in[8];
    float* out = (float*)d_out;

    // Workspace layout (256B-aligned). Base ~58.7 MB; +19.2 MB for the
    // transform-first layer-2 fast path (gated on ws_size).
    char* ws = (char*)d_ws;
    size_t o = 0;
    auto alloc = [&](size_t bytes) {
        size_t p = o;
        o += (bytes + 255) & ~(size_t)255;
        return p;
    };
    int* deg = (int*)(ws + alloc((size_t)NR * NN * 4));                          // 0.6 MB
    unsigned short* slots = (unsigned short*)(ws + alloc((size_t)NR * NN * SLOT * 2)); // 19.2 MB
    unsigned short* xb = (unsigned short*)(ws + alloc((size_t)(NN + 1) * 96 * 2)); // 9.6 MB
    unsigned short* aggb = (unsigned short*)(ws + alloc((size_t)NR * NN * 96 * 2)); // 28.8 MB
    unsigned short* wt = (unsigned short*)(ws + alloc((size_t)WT_ELEMS * 2));    // 0.18 MB
    unsigned short* order = (unsigned short*)(ws + alloc((size_t)NWIN * 256 * 2)); // 0.3 MB
    size_t need_base = o;
    unsigned short* aggY2 = (unsigned short*)(ws + alloc((size_t)NR * NN * DOUT * 2)); // 19.2 MB
    size_t need_fast = o;
    const bool fast2 = (ws_size >= need_fast);
    (void)need_base;

    unsigned short* wt1s = wt;                         // [3][96][96]
    unsigned short* wt1n = wt1s + NR * DIN * DH;
    unsigned short* wt2s = wt1n + NR * DIN * DH;       // [3][64][96]
    unsigned short* wt2n = wt2s + NR * DH * DOUT;
    // Binning scratch aliases aggb (binning completes before agg writes aggb)
    unsigned int* gbuck = (unsigned int*)aggb;
    int* glofs = (int*)((char*)aggb + (size_t)NR * P1B * BSTRIDE * 4);
    // y2 tables (19.2 MB) alias aggb: aggb's layer-1 contents are dead after
    // the layer-1 mfma kernel has consumed them.
    unsigned short* y2 = aggb;

    // --- fused prep + binning ---
    prep_kernel<<<PREP_GRID, 512, 0, stream>>>(
        src, dst, gbuck, glofs, x, xb, Ws1, Wn1, Ws2, Wn2, wt);
    bin_build_kernel<<<NWIN, 512, 0, stream>>>(gbuck, glofs, slots, deg, order);

    constexpr int AGG_GRID  = NWIN * 16;               // 9408
    constexpr int GEMM_GRID = (NN + 63) / 64;          // 782

    // --- Layer 1: h1 (bf16, in place over xb) ---
    agg96_kernel<<<AGG_GRID, 256, 0, stream>>>(
        (const unsigned int*)xb, slots, deg, order, (unsigned int*)aggb);
    mfma_layer_kernel<DH, true, false><<<GEMM_GRID, 256, 0, stream>>>(
        xb, aggb, nullptr, wt1s, wt1n, b1, xb, (float*)nullptr);

    // --- Layer 2 ---
    if (fast2) {
        // transform-first: y2_r = h1@Wn2_r, then 64-wide gather, then Ws+add
        y2_kernel<<<GEMM_GRID, 256, 0, stream>>>(xb, wt2n, y2);
        agg64_kernel<<<AGG_GRID, 256, 0, stream>>>(
            (const unsigned int*)y2, slots, deg, order, (unsigned int*)aggY2);
        mfma_layer_kernel<DOUT, false, true><<<GEMM_GRID, 256, 0, stream>>>(
            xb, nullptr, aggY2, wt2s, wt2n, b2, (unsigned short*)nullptr, out);
    } else {
        agg96_kernel<<<AGG_GRID, 256, 0, stream>>>(
            (const unsigned int*)xb, slots, deg, order, (unsigned int*)aggb);
        mfma_layer_kernel<DOUT, false, false><<<GEMM_GRID, 256, 0, stream>>>(
            xb, aggb, nullptr, wt2s, wt2n, b2, (unsigned short*)nullptr, out);
    }
}

// Round 10
// 218.073 us; speedup vs baseline: 1.0348x; 1.0348x over previous
//
#include <hip/hip_runtime.h>
#include <hip/hip_bf16.h>

// Problem constants (fixed by reference)
constexpr int NN   = 50000;   // nodes
constexpr int NE   = 800000;  // edges per relation
constexpr int NR   = 3;       // relations
constexpr int DIN  = 96;
constexpr int DH   = 96;
constexpr int DOUT = 64;
constexpr int SLOT = 64;      // max in-degree slots (Poisson(16): P(>64) ~ 1e-22)
constexpr int ZROW = NN;      // reserved all-zero feature row (padding target)

// Binning parameters (zero global atomics; block-private runs + scan offsets)
constexpr int NBUCK   = 196;       // bucket = dst >> 8 (256 nodes per bucket)
constexpr int LCAP    = 56;        // per-(block,bucket) cap
constexpr int P1B     = 256;       // scatter blocks per relation
constexpr int CHUNK   = NE / P1B;  // 3125 edges per block (exact)
constexpr int BSTRIDE = 3200;      // gbuck ints per block
constexpr int LSTRIDE = 200;       // lofs ints per block (197 used)

// Fused prep kernel block ranges
constexpr int SCAT_BLKS = NR * P1B;                 // 768
constexpr int CONV_BLKS = (NN * 96 + 4095) / 4096;  // 1172
constexpr int WT_ELEMS  = 2 * NR * DIN * DH + 2 * NR * DH * DOUT;  // 92160
constexpr int WT_BLKS   = (WT_ELEMS + 511) / 512;   // 180
constexpr int PREP_GRID = SCAT_BLKS + CONV_BLKS + WT_BLKS;

typedef __attribute__((ext_vector_type(8))) short bf16x8;  // MFMA A/B frag
typedef __attribute__((ext_vector_type(4))) float f32x4;   // MFMA C/D frag

// ---- bf16 helpers (RNE) ----------------------------------------------------
__device__ __forceinline__ unsigned short f2b(float f) {
    unsigned int u = __float_as_uint(f);
    u += 0x7fffu + ((u >> 16) & 1u);
    return (unsigned short)(u >> 16);
}
__device__ __forceinline__ float blo(unsigned int u) { return __uint_as_float(u << 16); }
__device__ __forceinline__ float bhi(unsigned int u) { return __uint_as_float(u & 0xffff0000u); }
__device__ __forceinline__ unsigned int pack2(float lo, float hi) {
    return (unsigned int)f2b(lo) | ((unsigned int)f2b(hi) << 16);
}

struct __align__(4) U3 { unsigned int x, y, z; };

// ---------------------------------------------------------------------------
// Fused prep: [0,768) edge scatter; [768,1940) x f32->bf16 (+zero row);
// [1940,2120) weight transposes f32->bf16.
// ---------------------------------------------------------------------------
__global__ __launch_bounds__(512)
void prep_kernel(const int* __restrict__ src,
                 const int* __restrict__ dst,
                 unsigned int* __restrict__ gbuck,
                 int* __restrict__ glofs,
                 const float* __restrict__ x,
                 unsigned short* __restrict__ xb,    // [(NN+1)][96]
                 const float* __restrict__ Ws1, const float* __restrict__ Wn1,
                 const float* __restrict__ Ws2, const float* __restrict__ Wn2,
                 unsigned short* __restrict__ wt)
{
    __shared__ unsigned int lbuf[NBUCK][LCAP];
    __shared__ int lcnt[NBUCK];
    __shared__ int sa[256], sb[256];
    __shared__ int lofs[NBUCK + 1];

    const int bid = blockIdx.x;
    const int tid = threadIdx.x;

    if (bid < SCAT_BLKS) {
        const int r = bid >> 8, c = bid & 255;
        for (int i = tid; i < NBUCK; i += 512) lcnt[i] = 0;
        __syncthreads();

        const int* sr = src + (size_t)r * NE + (size_t)c * CHUNK;
        const int* dr = dst + (size_t)r * NE + (size_t)c * CHUNK;
        for (int i = tid; i < CHUNK; i += 512) {
            int d = dr[i];
            int s = sr[i];
            int b = d >> 8;
            int pos = atomicAdd(&lcnt[b], 1);
            if (pos < LCAP)
                lbuf[b][pos] = ((unsigned int)(d & 255) << 16) | (unsigned int)s;
        }
        __syncthreads();

        if (tid < 256)
            sa[tid] = (tid < NBUCK) ? min(lcnt[tid], LCAP) : 0;
        __syncthreads();
        int* cur = sa; int* nxt = sb;
        for (int st = 1; st < 256; st <<= 1) {
            if (tid < 256) {
                int v = cur[tid];
                if (tid >= st) v += cur[tid - st];
                nxt[tid] = v;
            }
            __syncthreads();
            int* t2 = cur; cur = nxt; nxt = t2;
        }
        if (tid == 0) lofs[0] = 0;
        if (tid < NBUCK) lofs[tid + 1] = cur[tid];
        __syncthreads();

        if (tid < NBUCK + 1) glofs[(size_t)bid * LSTRIDE + tid] = lofs[tid];

        const int w = tid >> 6, l = tid & 63;
        unsigned int* gb = gbuck + (size_t)bid * BSTRIDE;
        for (int b = w; b < NBUCK; b += 8) {
            int cnt = min(lcnt[b], LCAP);
            if (l < cnt) gb[lofs[b] + l] = lbuf[b][l];
        }
    } else if (bid < SCAT_BLKS + CONV_BLKS) {
        const int rb = bid - SCAT_BLKS;
        if (rb == 0 && tid < 48) {
            unsigned int* z = reinterpret_cast<unsigned int*>(xb + (size_t)ZROW * 96);
            z[tid] = 0u;
        }
        int i = (rb * 512 + tid) * 8;
        if (i < NN * 96) {
            float4 a = *reinterpret_cast<const float4*>(x + i);
            float4 b = *reinterpret_cast<const float4*>(x + i + 4);
            uint4 o;
            o.x = pack2(a.x, a.y);
            o.y = pack2(a.z, a.w);
            o.z = pack2(b.x, b.y);
            o.w = pack2(b.z, b.w);
            *reinterpret_cast<uint4*>(xb + i) = o;
        }
    } else {
        int g = (bid - SCAT_BLKS - CONV_BLKS) * 512 + tid;
        if (g < WT_ELEMS) {
            constexpr int SZ1 = NR * DIN * DH;
            constexpr int SZ2 = NR * DH * DOUT;
            const float* in;
            int idx, KD, ND;
            if (g < SZ1)                { in = Ws1; idx = g;                 KD = DIN; ND = DH; }
            else if (g < 2 * SZ1)       { in = Wn1; idx = g - SZ1;           KD = DIN; ND = DH; }
            else if (g < 2 * SZ1 + SZ2) { in = Ws2; idx = g - 2 * SZ1;       KD = DH;  ND = DOUT; }
            else                        { in = Wn2; idx = g - 2 * SZ1 - SZ2; KD = DH;  ND = DOUT; }
            int k = idx % KD;
            int rn = idx / KD;
            int n = rn % ND;
            int r = rn / ND;
            wt[g] = f2b(in[((size_t)r * KD + k) * ND + n]);
        }
    }
}

// ---------------------------------------------------------------------------
// Binning phase B: one block per (relation,bucket). LDS-bin into 256-node
// slot lists (ZROW-padded), write slots + deg fully coalesced. (round-8 form)
// ---------------------------------------------------------------------------
__global__ __launch_bounds__(512)
void bin_build_kernel(const unsigned int* __restrict__ gbuck,
                      const int* __restrict__ glofs,
                      unsigned short* __restrict__ slots,   // [NR*NN][SLOT]
                      int* __restrict__ deg)                // [NR*NN]
{
    __shared__ unsigned short lslot[256][SLOT];   // 32 KB
    __shared__ int lcnt[256];

    const int rb = blockIdx.x;
    const int r  = rb / NBUCK, b = rb - r * NBUCK;
    const int nbase = b * 256;
    int nb = NN - nbase; if (nb > 256) nb = 256;
    const int tid = threadIdx.x;

    unsigned int* ls32i = reinterpret_cast<unsigned int*>(&lslot[0][0]);
    for (int i = tid; i < 256 * SLOT / 2; i += 512) ls32i[i] = 0xC350C350u; // ZROW pad
    for (int i = tid; i < 256; i += 512) lcnt[i] = 0;
    __syncthreads();

    const int blk  = tid >> 1;
    const int half = tid & 1;
    const int gblk = r * P1B + blk;
    int o0 = glofs[(size_t)gblk * LSTRIDE + b];
    int o1 = glofs[(size_t)gblk * LSTRIDE + b + 1];
    const unsigned int* run = gbuck + (size_t)gblk * BSTRIDE + o0;
    int cnt = o1 - o0;
    for (int i = half; i < cnt; i += 2) {
        unsigned int e = run[i];
        int nl = e >> 16;
        int pos = atomicAdd(&lcnt[nl], 1);
        if (pos < SLOT) lslot[nl][pos] = (unsigned short)(e & 0xffffu);
    }
    __syncthreads();

    for (int j = tid; j < nb; j += 512) deg[r * NN + nbase + j] = lcnt[j];

    const unsigned int* ls32 = reinterpret_cast<const unsigned int*>(&lslot[0][0]);
    unsigned int* gs32 = reinterpret_cast<unsigned int*>(
        slots + ((size_t)r * NN + nbase) * SLOT);
    const int tot = nb * (SLOT / 2);
    for (int i = tid; i < tot; i += 512) gs32[i] = ls32[i];
}

// ---------------------------------------------------------------------------
// Mean-aggregation, 96-dim rows (layer 1). 16 lanes per (rel,node); lane t
// gathers 12B of each 192B row; branch-free 8-edge batches, ZROW padding.
// ---------------------------------------------------------------------------
__global__ __launch_bounds__(256)
void agg96_kernel(const unsigned int* __restrict__ Hb,        // [(NN+1)][48]
                  const unsigned short* __restrict__ slots,
                  const int* __restrict__ deg,
                  unsigned int* __restrict__ aggb)            // [NR][NN][48]
{
    int gid = blockIdx.x * 256 + threadIdx.x;
    int grp = gid >> 4, t = gid & 15;
    if (grp >= NR * NN) return;
    const uint4* sl4 = reinterpret_cast<const uint4*>(slots + (size_t)grp * SLOT);
    int e = deg[grp];
    if (e > SLOT) e = SLOT;

    uint4 iv0 = sl4[0], iv1 = sl4[1], iv2 = sl4[2], iv3 = sl4[3];
    float a0 = 0.f, a1 = 0.f, a2 = 0.f, a3 = 0.f, a4 = 0.f, a5 = 0.f;

#define DO8(V)                                                                 \
    {                                                                          \
        unsigned int i0 = (V).x & 0xffffu, i1 = (V).x >> 16;                   \
        unsigned int i2 = (V).y & 0xffffu, i3 = (V).y >> 16;                   \
        unsigned int i4 = (V).z & 0xffffu, i5 = (V).z >> 16;                   \
        unsigned int i6 = (V).w & 0xffffu, i7 = (V).w >> 16;                   \
        U3 g0 = *reinterpret_cast<const U3*>(Hb + (size_t)i0 * 48 + 3 * t);    \
        U3 g1 = *reinterpret_cast<const U3*>(Hb + (size_t)i1 * 48 + 3 * t);    \
        U3 g2 = *reinterpret_cast<const U3*>(Hb + (size_t)i2 * 48 + 3 * t);    \
        U3 g3 = *reinterpret_cast<const U3*>(Hb + (size_t)i3 * 48 + 3 * t);    \
        U3 g4 = *reinterpret_cast<const U3*>(Hb + (size_t)i4 * 48 + 3 * t);    \
        U3 g5 = *reinterpret_cast<const U3*>(Hb + (size_t)i5 * 48 + 3 * t);    \
        U3 g6 = *reinterpret_cast<const U3*>(Hb + (size_t)i6 * 48 + 3 * t);    \
        U3 g7 = *reinterpret_cast<const U3*>(Hb + (size_t)i7 * 48 + 3 * t);    \
        a0 += blo(g0.x) + blo(g1.x) + blo(g2.x) + blo(g3.x)                    \
            + blo(g4.x) + blo(g5.x) + blo(g6.x) + blo(g7.x);                   \
        a1 += bhi(g0.x) + bhi(g1.x) + bhi(g2.x) + bhi(g3.x)                    \
            + bhi(g4.x) + bhi(g5.x) + bhi(g6.x) + bhi(g7.x);                   \
        a2 += blo(g0.y) + blo(g1.y) + blo(g2.y) + blo(g3.y)                    \
            + blo(g4.y) + blo(g5.y) + blo(g6.y) + blo(g7.y);                   \
        a3 += bhi(g0.y) + bhi(g1.y) + bhi(g2.y) + bhi(g3.y)                    \
            + bhi(g4.y) + bhi(g5.y) + bhi(g6.y) + bhi(g7.y);                   \
        a4 += blo(g0.z) + blo(g1.z) + blo(g2.z) + blo(g3.z)                    \
            + blo(g4.z) + blo(g5.z) + blo(g6.z) + blo(g7.z);                   \
        a5 += bhi(g0.z) + bhi(g1.z) + bhi(g2.z) + bhi(g3.z)                    \
            + bhi(g4.z) + bhi(g5.z) + bhi(g6.z) + bhi(g7.z);                   \
    }

    int nb8 = (e + 7) >> 3;
    if (nb8 > 0) DO8(iv0);
    if (nb8 > 1) DO8(iv1);
    if (nb8 > 2) DO8(iv2);
    if (nb8 > 3) DO8(iv3);
    for (int i = 32; i < e; i += 8) {
        uint4 v = sl4[i >> 3];
        DO8(v);
    }
#undef DO8

    float inv = 1.0f / (float)(e > 0 ? e : 1);
    unsigned int* o = aggb + (size_t)grp * 48 + 3 * t;
    o[0] = pack2(a0 * inv, a1 * inv);
    o[1] = pack2(a2 * inv, a3 * inv);
    o[2] = pack2(a4 * inv, a5 * inv);
}

// ---------------------------------------------------------------------------
// Mean-aggregation of Wn2-TRANSFORMED 64-dim rows (layer 2), one relation.
// Gathers 128B rows from the 6.4MB y2 slot; lane t reads 8B per row.
// ---------------------------------------------------------------------------
__global__ __launch_bounds__(256)
void agg64_kernel(const unsigned int* __restrict__ Tp,         // y2 [(NN+1)][32]
                  const unsigned short* __restrict__ slots_r,  // [NN][SLOT]
                  const int* __restrict__ deg_r,               // [NN]
                  unsigned int* __restrict__ outb)             // [NN][32]
{
    int gid = blockIdx.x * 256 + threadIdx.x;
    int g = gid >> 4, t = gid & 15;
    if (g >= NN) return;
    const uint4* sl4 = reinterpret_cast<const uint4*>(slots_r + (size_t)g * SLOT);
    int e = deg_r[g];
    if (e > SLOT) e = SLOT;

    uint4 iv0 = sl4[0], iv1 = sl4[1], iv2 = sl4[2], iv3 = sl4[3];
    float a0 = 0.f, a1 = 0.f, a2 = 0.f, a3 = 0.f;

#define DO8W(V)                                                                \
    {                                                                          \
        unsigned int i0 = (V).x & 0xffffu, i1 = (V).x >> 16;                   \
        unsigned int i2 = (V).y & 0xffffu, i3 = (V).y >> 16;                   \
        unsigned int i4 = (V).z & 0xffffu, i5 = (V).z >> 16;                   \
        unsigned int i6 = (V).w & 0xffffu, i7 = (V).w >> 16;                   \
        uint2 g0 = *reinterpret_cast<const uint2*>(Tp + (size_t)i0 * 32 + 2 * t); \
        uint2 g1 = *reinterpret_cast<const uint2*>(Tp + (size_t)i1 * 32 + 2 * t); \
        uint2 g2 = *reinterpret_cast<const uint2*>(Tp + (size_t)i2 * 32 + 2 * t); \
        uint2 g3 = *reinterpret_cast<const uint2*>(Tp + (size_t)i3 * 32 + 2 * t); \
        uint2 g4 = *reinterpret_cast<const uint2*>(Tp + (size_t)i4 * 32 + 2 * t); \
        uint2 g5 = *reinterpret_cast<const uint2*>(Tp + (size_t)i5 * 32 + 2 * t); \
        uint2 g6 = *reinterpret_cast<const uint2*>(Tp + (size_t)i6 * 32 + 2 * t); \
        uint2 g7 = *reinterpret_cast<const uint2*>(Tp + (size_t)i7 * 32 + 2 * t); \
        a0 += blo(g0.x) + blo(g1.x) + blo(g2.x) + blo(g3.x)                    \
            + blo(g4.x) + blo(g5.x) + blo(g6.x) + blo(g7.x);                   \
        a1 += bhi(g0.x) + bhi(g1.x) + bhi(g2.x) + bhi(g3.x)                    \
            + bhi(g4.x) + bhi(g5.x) + bhi(g6.x) + bhi(g7.x);                   \
        a2 += blo(g0.y) + blo(g1.y) + blo(g2.y) + blo(g3.y)                    \
            + blo(g4.y) + blo(g5.y) + blo(g6.y) + blo(g7.y);                   \
        a3 += bhi(g0.y) + bhi(g1.y) + bhi(g2.y) + bhi(g3.y)                    \
            + bhi(g4.y) + bhi(g5.y) + bhi(g6.y) + bhi(g7.y);                   \
    }

    int nb8 = (e + 7) >> 3;
    if (nb8 > 0) DO8W(iv0);
    if (nb8 > 1) DO8W(iv1);
    if (nb8 > 2) DO8W(iv2);
    if (nb8 > 3) DO8W(iv3);
    for (int i = 32; i < e; i += 8) {
        uint4 v = sl4[i >> 3];
        DO8W(v);
    }
#undef DO8W

    float inv = 1.0f / (float)(e > 0 ? e : 1);
    unsigned int* o = outb + (size_t)g * 32 + 2 * t;
    o[0] = pack2(a0 * inv, a1 * inv);
    o[1] = pack2(a2 * inv, a3 * inv);
}

// ---------------------------------------------------------------------------
// y2 = h1 @ Wn2_r for ONE relation (dense MFMA), bf16 out, ZROW row zeroed.
// ---------------------------------------------------------------------------
__global__ __launch_bounds__(256)
void y2_kernel(const unsigned short* __restrict__ Hb,    // h1 [(NN+1)][96]
               const unsigned short* __restrict__ Wtn_r, // [64][96] (Wn2_r^T)
               unsigned short* __restrict__ y2)          // [(NN+1)][64]
{
    if (blockIdx.x == 0 && threadIdx.x < 32) {
        unsigned int* z = reinterpret_cast<unsigned int*>(y2 + (size_t)ZROW * 64);
        z[threadIdx.x] = 0u;
    }
    const int w    = threadIdx.x >> 6;
    const int l    = threadIdx.x & 63;
    const int n0   = blockIdx.x * 64 + w * 16;
    const int arow = l & 15, asel = l >> 4;
    int na = n0 + arow;
    if (na > NN - 1) na = NN - 1;

    bf16x8 ax[3];
    const unsigned short* xr = Hb + (size_t)na * 96 + asel * 8;
    #pragma unroll
    for (int kb = 0; kb < 3; ++kb)
        ax[kb] = *reinterpret_cast<const bf16x8*>(xr + kb * 32);

    #pragma unroll
    for (int c = 0; c < 4; ++c) {
        f32x4 acc = (f32x4){0.f, 0.f, 0.f, 0.f};
        const unsigned short* bn = Wtn_r + ((size_t)(c * 16 + arow)) * 96 + asel * 8;
        #pragma unroll
        for (int kb = 0; kb < 3; ++kb)
            acc = __builtin_amdgcn_mfma_f32_16x16x32_bf16(
                ax[kb], *reinterpret_cast<const bf16x8*>(bn + kb * 32), acc, 0, 0, 0);
        const int col = c * 16 + arow;
        #pragma unroll
        for (int j = 0; j < 4; ++j) {
            int node = n0 + asel * 4 + j;
            if (node < NN)
                y2[(size_t)node * 64 + col] = f2b(acc[j]);
        }
    }
}

// ---------------------------------------------------------------------------
// MFMA layer. PRE_AGG=false: acc = X@Ws_r + AGG_r@Wn_r (aggb raw means).
// PRE_AGG=true:  acc initialized from pre-transformed aggY2_r; Ws MFMAs only.
// Layer 1 writes o16 IN PLACE over Hb (each row read only by its owner wave
// before its stores; ZROW never written -> stays zero for layer 2).
// ---------------------------------------------------------------------------
template <int NOUT, bool OUT16, bool PRE_AGG>
__global__ __launch_bounds__(256)
void mfma_layer_kernel(const unsigned short* Hb,                // [(NN+1)][96] (may alias o16)
                       const unsigned short* __restrict__ aggb, // [NR][NN][96] (if !PRE_AGG)
                       const unsigned short* __restrict__ aggY2,// [NR][NN][NOUT] (if PRE_AGG)
                       const unsigned short* __restrict__ Wts,  // [NR][NOUT][96]
                       const unsigned short* __restrict__ Wtn,  // [NR][NOUT][96]
                       const float* __restrict__ bias,          // [NR][NOUT]
                       unsigned short* o16,                     // [(NN+1)][96]
                       float* __restrict__ o32)                 // [NN][NOUT]
{
    const int w    = threadIdx.x >> 6;
    const int l    = threadIdx.x & 63;
    const int n0   = blockIdx.x * 64 + w * 16;
    const int arow = l & 15, asel = l >> 4;
    int na = n0 + arow;
    if (na > NN - 1) na = NN - 1;

    bf16x8 ax[3], ag[NR][3];
    {
        const unsigned short* xr = Hb + (size_t)na * 96 + asel * 8;
        #pragma unroll
        for (int kb = 0; kb < 3; ++kb)
            ax[kb] = *reinterpret_cast<const bf16x8*>(xr + kb * 32);
        if (!PRE_AGG) {
            #pragma unroll
            for (int r = 0; r < NR; ++r) {
                const unsigned short* gr = aggb + ((size_t)r * NN + na) * 96 + asel * 8;
                #pragma unroll
                for (int kb = 0; kb < 3; ++kb)
                    ag[r][kb] = *reinterpret_cast<const bf16x8*>(gr + kb * 32);
            }
        }
    }

    constexpr int NC = NOUT / 16;
    #pragma unroll
    for (int c = 0; c < NC; ++c) {
        const int col = c * 16 + arow;
        f32x4 acc[NR];
        if (PRE_AGG) {
            #pragma unroll
            for (int r = 0; r < NR; ++r)
                #pragma unroll
                for (int j = 0; j < 4; ++j) {
                    int nj = n0 + asel * 4 + j;
                    if (nj > NN - 1) nj = NN - 1;
                    unsigned short hv = aggY2[((size_t)r * NN + nj) * NOUT + col];
                    acc[r][j] = __uint_as_float((unsigned int)hv << 16);
                }
        } else {
            #pragma unroll
            for (int r = 0; r < NR; ++r) acc[r] = (f32x4){0.f, 0.f, 0.f, 0.f};
        }

        #pragma unroll
        for (int r = 0; r < NR; ++r) {
            const unsigned short* bs = Wts + ((size_t)r * NOUT + c * 16 + arow) * 96 + asel * 8;
            #pragma unroll
            for (int kb = 0; kb < 3; ++kb) {
                acc[r] = __builtin_amdgcn_mfma_f32_16x16x32_bf16(
                    ax[kb], *reinterpret_cast<const bf16x8*>(bs + kb * 32), acc[r], 0, 0, 0);
                if (!PRE_AGG) {
                    const unsigned short* bn = Wtn + ((size_t)r * NOUT + c * 16 + arow) * 96 + asel * 8;
                    acc[r] = __builtin_amdgcn_mfma_f32_16x16x32_bf16(
                        ag[r][kb], *reinterpret_cast<const bf16x8*>(bn + kb * 32), acc[r], 0, 0, 0);
                }
            }
        }

        const float b0 = bias[col];
        const float b1 = bias[NOUT + col];
        const float b2 = bias[2 * NOUT + col];
        #pragma unroll
        for (int j = 0; j < 4; ++j) {
            int node = n0 + asel * 4 + j;
            if (node < NN) {
                float v = (tanhf(acc[0][j] + b0) + tanhf(acc[1][j] + b1)
                         + tanhf(acc[2][j] + b2)) * (1.0f / 3.0f);
                if (OUT16) o16[(size_t)node * 96 + col] = f2b(v);
                else       o32[(size_t)node * DOUT + col] = v;
            }
        }
    }
}

// ---------------------------------------------------------------------------
extern "C" void kernel_launch(void* const* d_in, const int* in_sizes, int n_in,
                              void* d_out, int out_size, void* d_ws, size_t ws_size,
                              hipStream_t stream)
{
    const float* x   = (const float*)d_in[0];
    const int*   src = (const int*)d_in[1];
    const int*   dst = (const int*)d_in[2];
    const float* Ws1 = (const float*)d_in[3];
    const float* Wn1 = (const float*)d_in[4];
    const float* b1  = (const float*)d_in[5];
    const float* Ws2 = (const float*)d_in[6];
    const float* Wn2 = (const float*)d_in[7];
    const float* b2  = (const float*)d_in[8];
    float* out = (float*)d_out;

    // Workspace layout (256B-aligned), ~58.4 MB (round-8-proven size).
    char* ws = (char*)d_ws;
    size_t o = 0;
    auto alloc = [&](size_t bytes) {
        size_t p = o;
        o += (bytes + 255) & ~(size_t)255;
        return p;
    };
    int* deg = (int*)(ws + alloc((size_t)NR * NN * 4));                          // 0.6 MB
    unsigned short* slots = (unsigned short*)(ws + alloc((size_t)NR * NN * SLOT * 2)); // 19.2 MB
    unsigned short* xb = (unsigned short*)(ws + alloc((size_t)(NN + 1) * 96 * 2)); // 9.6 MB
    char* aggregion = ws + alloc((size_t)NR * NN * 96 * 2);                      // 28.8 MB
    unsigned short* wt = (unsigned short*)(ws + alloc((size_t)WT_ELEMS * 2));    // 0.18 MB
    unsigned short* wt1s = wt;                         // [3][96][96]
    unsigned short* wt1n = wt1s + NR * DIN * DH;
    unsigned short* wt2s = wt1n + NR * DIN * DH;       // [3][64][96]
    unsigned short* wt2n = wt2s + NR * DH * DOUT;

    // aggregion time-multiplexed uses (all sequential on one stream):
    //  (1) binning scratch: gbuck 9.83MB + glofs 0.61MB
    //  (2) layer-1 aggb [3][NN][96] bf16 = 28.8MB
    //  (3) layer-2: y2 slot [(NN+1)][64] 6.4MB + aggY2 [3][NN][64] 19.2MB = 25.6MB
    unsigned int* gbuck = (unsigned int*)aggregion;
    int* glofs = (int*)(aggregion + (size_t)NR * P1B * BSTRIDE * 4);
    unsigned short* aggb = (unsigned short*)aggregion;
    unsigned short* y2 = (unsigned short*)aggregion;                       // 6.4 MB
    unsigned short* aggY2 = (unsigned short*)(aggregion + (size_t)(NN + 1) * 64 * 2 + 256);

    // --- fused prep + binning ---
    prep_kernel<<<PREP_GRID, 512, 0, stream>>>(
        src, dst, gbuck, glofs, x, xb, Ws1, Wn1, Ws2, Wn2, wt);
    bin_build_kernel<<<NR * NBUCK, 512, 0, stream>>>(gbuck, glofs, slots, deg);

    constexpr int AGG96_GRID = NR * NN * 16 / 256;     // 9375
    constexpr int AGG64_GRID = NN * 16 / 256;          // 3125
    constexpr int GEMM_GRID  = (NN + 63) / 64;         // 782

    // --- Layer 1: h1 (bf16, in place over xb) ---
    agg96_kernel<<<AGG96_GRID, 256, 0, stream>>>(
        (const unsigned int*)xb, slots, deg, (unsigned int*)aggb);
    mfma_layer_kernel<DH, true, false><<<GEMM_GRID, 256, 0, stream>>>(
        xb, aggb, nullptr, wt1s, wt1n, b1, xb, (float*)nullptr);

    // --- Layer 2 (transform-first, relation-sequential; fits in aggregion) ---
    for (int r = 0; r < NR; ++r) {
        y2_kernel<<<GEMM_GRID, 256, 0, stream>>>(
            xb, wt2n + (size_t)r * DOUT * 96, y2);
        agg64_kernel<<<AGG64_GRID, 256, 0, stream>>>(
            (const unsigned int*)y2,
            slots + (size_t)r * NN * SLOT,
            deg + (size_t)r * NN,
            (unsigned int*)(aggY2 + (size_t)r * NN * DOUT));
    }
    mfma_layer_kernel<DOUT, false, true><<<GEMM_GRID, 256, 0, stream>>>(
        xb, nullptr, aggY2, wt2s, wt2n, b2, (unsigned short*)nullptr, out);
}